// Round 3
// baseline (21956.245 us; speedup 1.0000x reference)
//
#include <hip/hip_runtime.h>
#include <math.h>

// Persistent cooperative 2-layer LSTM, fp32.
// B=64, T=512, D=128, H=512. Grid: 256 WGs x 256 threads, 1 WG/CU.
// WG w: bgrp = w&1 (batches bgrp*32..+32), cgrp = w>>1 (h-cols cgrp*4..+4).
// Thread: b = tid&31 (local batch), slot = tid>>5: cgp = slot&1 (2 cols), kh = slot>>1 (K quarter).
// Pipeline: iteration t computes layer0 step t, layer1 step t-1, y step t-2. 514 iterations.
//
// Round 3: contention-free barrier topology.
//  - arrival: flags[wg] on its OWN 64B line (256 lines), relaxed agent store.
//  - aggregate: WG0 wave0, each lane polls 4 distinct lines.
//  - release: WG0 lanes 0..31 write 32 replicated release lines; WG w polls
//    line (wg>>3) -> <=8 pollers per line (was 255 on one line: ~35us/iter).
//  - data: ring/out writes are relaxed agent atomics (write-through, never
//    dirty in L2); ring reads plain cached loads made safe by one agent
//    acquire fence (buffer_inv) per WG per barrier pass.
//
// ws layout (bytes): flags 256*64 @ 0; rel 32*64 @ 16384; floats @ 20480:
// ring0[2][64][512], ring1[2][64][512].

#define B64 64
#define TT 512
#define NWG 256

// smem offsets (floats)
#define SM_W0    0        // [4 cl][4 g][640]   = 10240
#define SM_W1    10240    // [4 cl][4 g][1024]  = 16384
#define SM_HT    26624    // float4 [32 k4][33] = 1056 f4 = 4224 fl
#define SM_RED   30848    // [3][2][32][8]      = 1536
#define SM_WLIN  32384    // 512
#define SM_YBUF  32896    // 256
#define SM_TOT   33152    // 132,608 B LDS

__device__ __forceinline__ float fsigmoid(float v){ return 1.f/(1.f+__expf(-v)); }
__device__ __forceinline__ float ftanh(float v){ return 2.f/(1.f+__expf(-2.f*v)) - 1.f; }

__device__ __forceinline__ void st_agent(float* p, float v){
  __hip_atomic_store(p, v, __ATOMIC_RELAXED, __HIP_MEMORY_SCOPE_AGENT);
}

__device__ __forceinline__ void gridbar(unsigned* flags, unsigned* rel,
                                        int wg, int tid, unsigned phase){
  // release: my ring stores (write-through) must be complete before my flag
  asm volatile("s_waitcnt vmcnt(0)" ::: "memory");
  __syncthreads();
  if (tid == 0)
    __hip_atomic_store(&flags[wg*16], phase, __ATOMIC_RELAXED, __HIP_MEMORY_SCOPE_AGENT);
  if (wg == 0 && tid < 64){
    for(;;){
      bool ok = true;
      #pragma unroll
      for (int i=0;i<4;i++){
        unsigned v = __hip_atomic_load(&flags[(tid*4+i)*16], __ATOMIC_RELAXED, __HIP_MEMORY_SCOPE_AGENT);
        ok &= (v >= phase);
      }
      if (__all(ok)) break;
      __builtin_amdgcn_s_sleep(2);
    }
    if (tid < 32)
      __hip_atomic_store(&rel[tid*16], phase, __ATOMIC_RELAXED, __HIP_MEMORY_SCOPE_AGENT);
  }
  if (tid == 0 && wg != 0){
    unsigned* myrel = &rel[(wg>>3)*16];
    while (__hip_atomic_load(myrel, __ATOMIC_RELAXED, __HIP_MEMORY_SCOPE_AGENT) < phase)
      __builtin_amdgcn_s_sleep(4);
  }
  __syncthreads();
  // acquire: invalidate stale L1/L2 lines (ring buffers) before cached reads
  __builtin_amdgcn_fence(__ATOMIC_ACQUIRE, "agent");
}

// Gate dot-products for one layer step. KT = number of 128-float K tiles (5 for L0, 8 for L1).
template<int KT>
__device__ __forceinline__ void gates_dot(
    float* smem, const float* Wl,
    const float4* __restrict__ srcA, const float4* __restrict__ srcB, int strideBf4,
    int tid, int b, int bgrp, int cgp, int kh, float acc[2][4])
{
  constexpr int K4 = KT*32;     // f4 per W row
  float4* ht4 = (float4*)(smem + SM_HT);
  const float4* W4 = (const float4*)Wl;

  float4 pf[4];
  #pragma unroll
  for (int j=0;j<4;j++){
    int fidx = tid + 256*j; int lb = fidx>>5; int k4 = fidx&31;
    int gb = bgrp*32 + lb;
    pf[j] = srcA[gb*128 + k4];
  }

  for (int kt=0; kt<KT; ++kt){
    __syncthreads();
    #pragma unroll
    for (int j=0;j<4;j++){
      int fidx = tid + 256*j; int lb = fidx>>5; int k4 = fidx&31;
      ht4[k4*33 + lb] = pf[j];
    }
    if (kt+1 < KT){
      #pragma unroll
      for (int j=0;j<4;j++){
        int fidx = tid + 256*j; int lb = fidx>>5; int k4 = fidx&31;
        int gb = bgrp*32 + lb; int gk4 = (kt+1)*32 + k4;
        pf[j] = (gk4 < 128) ? srcA[gb*128 + gk4]
                            : srcB[gb*strideBf4 + (gk4-128)];
      }
    }
    __syncthreads();
    #pragma unroll
    for (int q=0;q<8;q++){
      int k4l = kh*8 + q;
      float4 hv = ht4[k4l*33 + b];
      int kb = kt*32 + k4l;
      #pragma unroll
      for (int j=0;j<2;j++){
        int cl = cgp*2 + j;
        #pragma unroll
        for (int g=0; g<4; ++g){
          float4 wv = W4[(cl*4+g)*K4 + kb];
          acc[j][g] += hv.x*wv.x + hv.y*wv.y + hv.z*wv.z + hv.w*wv.w;
        }
      }
    }
  }
}

__device__ __forceinline__ void reduce_cell(
    float* smem, float acc[2][4], int b, int cgp, int kh,
    int bb, int colbase, float* cr, float* __restrict__ ringw)
{
  float* red = smem + SM_RED;
  if (kh > 0){
    float* dst = red + ((kh-1)*64 + cgp*32 + b)*8;
    #pragma unroll
    for (int j=0;j<2;j++)
      #pragma unroll
      for (int g=0;g<4;g++) dst[j*4+g] = acc[j][g];
  }
  __syncthreads();
  if (kh == 0){
    #pragma unroll
    for (int r=0;r<3;r++){
      float* s = red + (r*64 + cgp*32 + b)*8;
      #pragma unroll
      for (int j=0;j<2;j++)
        #pragma unroll
        for (int g=0;g<4;g++) acc[j][g] += s[j*4+g];
    }
    #pragma unroll
    for (int j=0;j<2;j++){
      float gi = fsigmoid(acc[j][0]);
      float gf = fsigmoid(acc[j][1]);
      float gg = ftanh   (acc[j][2]);
      float go = fsigmoid(acc[j][3]);
      float c = gf*cr[j] + gi*gg;
      cr[j] = c;
      st_agent(&ringw[bb*512 + colbase + cgp*2 + j], go * ftanh(c));
    }
  }
}

__global__ __launch_bounds__(256, 1) void lstm_pers(
    const float* __restrict__ x,    const float* __restrict__ h0in, const float* __restrict__ c0in,
    const float* __restrict__ wih0, const float* __restrict__ whh0,
    const float* __restrict__ bih0, const float* __restrict__ bhh0,
    const float* __restrict__ wih1, const float* __restrict__ whh1,
    const float* __restrict__ bih1, const float* __restrict__ bhh1,
    const float* __restrict__ wlin, const float* __restrict__ blin,
    float* __restrict__ out, float* ws)
{
  __shared__ __align__(16) float smem[SM_TOT];
  const int tid = threadIdx.x, wg = blockIdx.x;
  const int b    = tid & 31;
  const int slot = tid >> 5;
  const int cgp  = slot & 1;
  const int kh   = slot >> 1;
  const int bgrp = wg & 1;
  const int cgrp = wg >> 1;
  const int colbase = cgrp*4;
  const int bb = bgrp*32 + b;

  unsigned* flags = (unsigned*)ws;                  // 256 lines of 64B
  unsigned* rel   = ((unsigned*)ws) + 4096;         // 32 lines of 64B @ byte 16384
  float* ring0 = ws + 5120;                         // @ byte 20480
  float* ring1 = ws + 5120 + 65536;

  // ---- load W slices into LDS (once) ----
  for (int idx = tid; idx < 10240; idx += 256){
    int cl = idx / 2560; int rem = idx - cl*2560; int g = rem / 640; int k = rem - g*640;
    int r = g*512 + colbase + cl;
    smem[SM_W0 + idx] = (k < 512) ? whh0[r*512 + k] : wih0[r*128 + (k-512)];
  }
  for (int idx = tid; idx < 16384; idx += 256){
    int cl = idx >> 12; int g = (idx >> 10) & 3; int k = idx & 1023;
    int r = g*512 + colbase + cl;
    smem[SM_W1 + idx] = (k < 512) ? whh1[r*512 + k] : wih1[r*512 + (k-512)];
  }
  for (int idx = tid; idx < 512; idx += 256) smem[SM_WLIN + idx] = wlin[idx];

  // ---- per-thread persistent registers ----
  float bias0[2][4], bias1[2][4], c0r[2], c1r[2];
  #pragma unroll
  for (int j=0;j<2;j++){
    int col = colbase + cgp*2 + j;
    #pragma unroll
    for (int g=0;g<4;g++){
      bias0[j][g] = bih0[g*512+col] + bhh0[g*512+col];
      bias1[j][g] = bih1[g*512+col] + bhh1[g*512+col];
    }
    c0r[j] = c0in[          bb*512 + col];
    c1r[j] = c0in[32768   + bb*512 + col];
  }
  float blin_r = blin[0];

  // ---- init h rings (agent-scope stores: cross-XCD readers next iter) ----
  {
    int gidx = wg*256 + tid;            // [0, 65536)
    if (gidx < 32768) st_agent(&ring0[32768 + gidx], h0in[gidx]);
    else              st_agent(&ring1[32768 + (gidx - 32768)], h0in[gidx]);
  }

  unsigned phase = 1;
  gridbar(flags, rel, wg, tid, phase);

  // ---- main pipelined loop ----
  for (int t = 0; t <= TT+1; ++t){
    if (t < TT){  // layer 0, step t
      float acc[2][4];
      #pragma unroll
      for (int j=0;j<2;j++)
        #pragma unroll
        for (int g=0;g<4;g++) acc[j][g] = (kh==0) ? bias0[j][g] : 0.f;
      gates_dot<5>(smem, smem + SM_W0,
                   (const float4*)(ring0 + ((t+1)&1)*32768),
                   (const float4*)x + t*32, 16384,
                   tid, b, bgrp, cgp, kh, acc);
      reduce_cell(smem, acc, b, cgp, kh, bb, colbase, c0r, ring0 + (t&1)*32768);
    }
    if (t >= 1 && t <= TT){  // layer 1, step t-1
      float acc[2][4];
      #pragma unroll
      for (int j=0;j<2;j++)
        #pragma unroll
        for (int g=0;g<4;g++) acc[j][g] = (kh==0) ? bias1[j][g] : 0.f;
      gates_dot<8>(smem, smem + SM_W1,
                   (const float4*)(ring1 + (t&1)*32768),
                   (const float4*)(ring0 + ((t+1)&1)*32768), 128,
                   tid, b, bgrp, cgp, kh, acc);
      reduce_cell(smem, acc, b, cgp, kh, bb, colbase, c1r, ring1 + ((t+1)&1)*32768);
    }
    if (t >= 2 && cgrp == 0){  // y, step t-2
      int sy = t - 2;
      int yb = bgrp*32 + (tid & 31);
      const float4* row4 = (const float4*)(ring1 + (t&1)*32768 + yb*512) + (tid>>5)*16;
      const float4* wl4  = (const float4*)(smem + SM_WLIN) + (tid>>5)*16;
      float p = 0.f;
      #pragma unroll
      for (int j=0;j<16;j++){
        float4 v = row4[j]; float4 w = wl4[j];
        p += v.x*w.x + v.y*w.y + v.z*w.z + v.w*w.w;
      }
      smem[SM_YBUF + (tid&31)*8 + (tid>>5)] = p;
      __syncthreads();
      if (tid < 32){
        float s = 0.f;
        #pragma unroll
        for (int k=0;k<8;k++) s += smem[SM_YBUF + tid*8 + k];
        // agent store: keep out-lines out of L2 so per-iter buffer_inv can't drop them
        st_agent(&out[(bgrp*32 + tid)*512 + sy], s + blin_r);
      }
    }
    ++phase;
    gridbar(flags, rel, wg, tid, phase);
  }
}

extern "C" void kernel_launch(void* const* d_in, const int* in_sizes, int n_in,
                              void* d_out, int out_size, void* d_ws, size_t ws_size,
                              hipStream_t stream)
{
  (void)in_sizes; (void)n_in; (void)out_size; (void)ws_size;
  const float* x    = (const float*)d_in[0];
  const float* h0   = (const float*)d_in[1];
  const float* c0   = (const float*)d_in[2];
  const float* wih0 = (const float*)d_in[3];
  const float* whh0 = (const float*)d_in[4];
  const float* bih0 = (const float*)d_in[5];
  const float* bhh0 = (const float*)d_in[6];
  const float* wih1 = (const float*)d_in[7];
  const float* whh1 = (const float*)d_in[8];
  const float* bih1 = (const float*)d_in[9];
  const float* bhh1 = (const float*)d_in[10];
  const float* wlin = (const float*)d_in[11];
  const float* blin = (const float*)d_in[12];
  float* outp = (float*)d_out;
  float* wsp  = (float*)d_ws;

  // zero flags (16KB) + release lines (2KB); rings fully rewritten by the kernel
  hipMemsetAsync(d_ws, 0, 18432, stream);

  void* args[] = { &x, &h0, &c0, &wih0, &whh0, &bih0, &bhh0,
                   &wih1, &whh1, &bih1, &bhh1, &wlin, &blin, &outp, &wsp };
  hipLaunchCooperativeKernel((const void*)lstm_pers, dim3(NWG), dim3(256), args, 0, stream);
}

// Round 4
// 14042.459 us; speedup vs baseline: 1.5636x; 1.5636x over previous
//
#include <hip/hip_runtime.h>
#include <math.h>

// Persistent cooperative 2-layer LSTM, fp32. Round 4: LDS-instruction economy.
// B=64, T=512, D=128, H=512. Grid: 256 WGs x 256 threads, 1 WG/CU.
// WG w: bgrp = w&1 (batches bgrp*32..+32), cgrp = w>>1 (h-cols cgrp*4..+4).
// Thread: bg = tid>>5 (4 batches bg*4..+4), s = tid&31: cp = s&1 (2 cols),
//         kq = s>>1 (k4 slice {kq, kq+16} of each 32-f4 K tile).
// Inner loop: per f4-step 12 ds_read_b128 -> 128 FMAs (was 9 -> 32): 3x fewer
// LDS instrs (the round-3 bottleneck: ~3744 b128/CU/iter at ~10cy each).
// Cross-kq reduce: in-wave xor-shuffle butterfly (no LDS). One grid barrier
// per iteration (2-deep rings make it WAR/RAW-safe). 515 barriers total.
//
// ws layout (bytes): flags 256*64 @ 0; rel 32*64 @ 16384; floats @ 20480:
// ring0[2][64][512], ring1[2][64][512].

#define TT 512
#define NWG 256

// smem offsets (floats)
#define SM_W0    0        // [4 cl][4 g][640]   = 10240
#define SM_W1    10240    // [4 cl][4 g][1024]  = 16384
#define SM_HT    26624    // float4 [32 k4][33] = 1056 f4 = 4224 fl
#define SM_WLIN  30848    // 512
#define SM_TOT   31360    // 125,440 B LDS

__device__ __forceinline__ float fsigmoid(float v){ return 1.f/(1.f+__expf(-v)); }
__device__ __forceinline__ float ftanh(float v){ return 2.f/(1.f+__expf(-2.f*v)) - 1.f; }

__device__ __forceinline__ void st_agent(float* p, float v){
  __hip_atomic_store(p, v, __ATOMIC_RELAXED, __HIP_MEMORY_SCOPE_AGENT);
}

__device__ __forceinline__ void gridbar(unsigned* flags, unsigned* rel,
                                        int wg, int tid, unsigned phase){
  // release: my ring stores (write-through) must be complete before my flag
  asm volatile("s_waitcnt vmcnt(0)" ::: "memory");
  __syncthreads();
  if (tid == 0)
    __hip_atomic_store(&flags[wg*16], phase, __ATOMIC_RELAXED, __HIP_MEMORY_SCOPE_AGENT);
  if (wg == 0 && tid < 64){
    for(;;){
      bool ok = true;
      #pragma unroll
      for (int i=0;i<4;i++){
        unsigned v = __hip_atomic_load(&flags[(tid*4+i)*16], __ATOMIC_RELAXED, __HIP_MEMORY_SCOPE_AGENT);
        ok &= (v >= phase);
      }
      if (__all(ok)) break;
      __builtin_amdgcn_s_sleep(2);
    }
    if (tid < 32)
      __hip_atomic_store(&rel[tid*16], phase, __ATOMIC_RELAXED, __HIP_MEMORY_SCOPE_AGENT);
  }
  if (tid == 0 && wg != 0){
    unsigned* myrel = &rel[(wg>>3)*16];
    while (__hip_atomic_load(myrel, __ATOMIC_RELAXED, __HIP_MEMORY_SCOPE_AGENT) < phase)
      __builtin_amdgcn_s_sleep(4);
  }
  __syncthreads();
  // acquire: invalidate stale L1/L2 lines (ring buffers) before cached reads
  __builtin_amdgcn_fence(__ATOMIC_ACQUIRE, "agent");
}

// Gate dot-products for one layer step. KT = number of 128-float K tiles (5 for L0, 8 for L1).
// acc[i (batch)][j (col)][g (gate)] partial over this thread's k4 slice.
template<int KT>
__device__ __forceinline__ void gates_dot(
    float* smem, const float* Wl,
    const float4* __restrict__ srcA, const float4* __restrict__ srcB, int strideBf4,
    int tid, int bg, int cp, int kq, float acc[4][2][4])
{
  constexpr int K4 = KT*32;     // f4 per W row
  float4* ht4 = (float4*)(smem + SM_HT);
  const float4* W4 = (const float4*)Wl;
  const int bgrp = 0;           // srcA/srcB already offset per-WG batch group by caller
  (void)bgrp;

  float4 pf[4];
  #pragma unroll
  for (int j=0;j<4;j++){
    int fidx = tid + 256*j; int lb = fidx>>5; int k4 = fidx&31;
    pf[j] = srcA[lb*128 + k4];
  }

  for (int kt=0; kt<KT; ++kt){
    __syncthreads();
    #pragma unroll
    for (int j=0;j<4;j++){
      int fidx = tid + 256*j; int lb = fidx>>5; int k4 = fidx&31;
      ht4[k4*33 + lb] = pf[j];
    }
    if (kt+1 < KT){
      #pragma unroll
      for (int j=0;j<4;j++){
        int fidx = tid + 256*j; int lb = fidx>>5; int k4 = fidx&31;
        int gk4 = (kt+1)*32 + k4;
        pf[j] = (gk4 < 128) ? srcA[lb*128 + gk4]
                            : srcB[lb*strideBf4 + (gk4-128)];
      }
    }
    __syncthreads();
    #pragma unroll
    for (int q=0;q<2;q++){
      int k4l = kq + 16*q;
      float4 hv[4];
      #pragma unroll
      for (int i=0;i<4;i++) hv[i] = ht4[k4l*33 + bg*4 + i];
      int kb = kt*32 + k4l;
      #pragma unroll
      for (int j=0;j<2;j++){
        int cl = cp*2 + j;
        #pragma unroll
        for (int g=0; g<4; ++g){
          float4 wv = W4[(cl*4+g)*K4 + kb];
          #pragma unroll
          for (int i=0;i<4;i++)
            acc[i][j][g] += hv[i].x*wv.x + hv[i].y*wv.y + hv[i].z*wv.z + hv[i].w*wv.w;
        }
      }
    }
  }
}

// In-wave butterfly reduce over the 16 kq-threads (lane bits 1..4), then cell
// update. Thread kq ends owning (i,j) = (kq>>2, (kq>>1)&1), gates via pair
// exchange with kq^1. Static indexing throughout (no scratch).
__device__ __forceinline__ void reduce_cell_wave(
    const float acc[4][2][4], int kq, const float bias[4],
    float* cr, int bb_own, int col_own, float* __restrict__ ringw)
{
  float r16[16];
  { bool kb = (kq & 1) != 0;            // keep o-bit1 (g-bit1) == kq-bit0; mask 2
    #pragma unroll
    for (int t=0;t<16;t++){
      int i = t>>2, j = (t>>1)&1, gk = t&1;
      float lo = acc[i][j][gk];
      float hi = acc[i][j][2+gk];
      float send = kb ? lo : hi;
      float recv = __shfl_xor(send, 2, 64);
      r16[t] = (kb ? hi : lo) + recv;
    }
  }
  float r8[8];
  { bool kb = ((kq>>1) & 1) != 0;       // keep o-bit2 (j) == kq-bit1; mask 4
    #pragma unroll
    for (int t=0;t<8;t++){
      int b0 = t&1, h2 = t>>1;
      float lo = r16[b0 | (h2<<2)];
      float hi = r16[b0 | 2 | (h2<<2)];
      float send = kb ? lo : hi;
      float recv = __shfl_xor(send, 4, 64);
      r8[t] = (kb ? hi : lo) + recv;
    }
  }
  float r4[4];
  { bool kb = ((kq>>2) & 1) != 0;       // keep o-bit3 (i-bit0) == kq-bit2; mask 8
    #pragma unroll
    for (int t=0;t<4;t++){
      int b0 = t&1, h1 = t>>1;
      float lo = r8[b0 | (h1<<2)];
      float hi = r8[b0 | 2 | (h1<<2)];
      float send = kb ? lo : hi;
      float recv = __shfl_xor(send, 8, 64);
      r4[t] = (kb ? hi : lo) + recv;
    }
  }
  float r2[2];
  { bool kb = ((kq>>3) & 1) != 0;       // keep o-bit4 (i-bit1) == kq-bit3; mask 16
    #pragma unroll
    for (int t=0;t<2;t++){
      float lo = r4[t];
      float hi = r4[t | 2];
      float send = kb ? lo : hi;
      float recv = __shfl_xor(send, 16, 64);
      r2[t] = (kb ? hi : lo) + recv;
    }
  }
  // pair exchange (kq^1 holds the other 2 gates of the same (i,j))
  float oth0 = __shfl_xor(r2[0], 2, 64);
  float oth1 = __shfl_xor(r2[1], 2, 64);
  bool odd = (kq & 1) != 0;
  float gi = (odd ? oth0 : r2[0]) + bias[0];
  float gf = (odd ? oth1 : r2[1]) + bias[1];
  float gg = (odd ? r2[0] : oth0) + bias[2];
  float go = (odd ? r2[1] : oth1) + bias[3];
  gi = fsigmoid(gi); gf = fsigmoid(gf); gg = ftanh(gg); go = fsigmoid(go);
  float c = gf*(*cr) + gi*gg;
  *cr = c;
  if (!odd) st_agent(&ringw[bb_own*512 + col_own], go * ftanh(c));
}

__global__ __launch_bounds__(256, 1) void lstm_pers(
    const float* __restrict__ x,    const float* __restrict__ h0in, const float* __restrict__ c0in,
    const float* __restrict__ wih0, const float* __restrict__ whh0,
    const float* __restrict__ bih0, const float* __restrict__ bhh0,
    const float* __restrict__ wih1, const float* __restrict__ whh1,
    const float* __restrict__ bih1, const float* __restrict__ bhh1,
    const float* __restrict__ wlin, const float* __restrict__ blin,
    float* __restrict__ out, float* ws)
{
  __shared__ __align__(16) float smem[SM_TOT];
  const int tid = threadIdx.x, wg = blockIdx.x;
  const int bg   = tid >> 5;          // [0,8): 4 batches each
  const int s    = tid & 31;
  const int cp   = s & 1;             // col pair
  const int kq   = s >> 1;            // [0,16): k4 slice
  const int bgrp = wg & 1;
  const int cgrp = wg >> 1;
  const int colbase = cgrp*4;

  // post-reduction ownership
  const int i_own   = kq >> 2;
  const int j_own   = (kq >> 1) & 1;
  const int col_own = colbase + cp*2 + j_own;
  const int bb_own  = bgrp*32 + bg*4 + i_own;

  unsigned* flags = (unsigned*)ws;                  // 256 lines of 64B
  unsigned* rel   = ((unsigned*)ws) + 4096;         // 32 lines @ byte 16384
  float* ring0 = ws + 5120;                         // @ byte 20480
  float* ring1 = ws + 5120 + 65536;

  // ---- load W slices into LDS (once) ----
  for (int idx = tid; idx < 10240; idx += 256){
    int cl = idx / 2560; int rem = idx - cl*2560; int g = rem / 640; int k = rem - g*640;
    int r = g*512 + colbase + cl;
    smem[SM_W0 + idx] = (k < 512) ? whh0[r*512 + k] : wih0[r*128 + (k-512)];
  }
  for (int idx = tid; idx < 16384; idx += 256){
    int cl = idx >> 12; int g = (idx >> 10) & 3; int k = idx & 1023;
    int r = g*512 + colbase + cl;
    smem[SM_W1 + idx] = (k < 512) ? whh1[r*512 + k] : wih1[r*512 + (k-512)];
  }
  for (int idx = tid; idx < 512; idx += 256) smem[SM_WLIN + idx] = wlin[idx];

  // ---- per-thread persistent state ----
  float bias0[4], bias1[4], c0r, c1r;
  #pragma unroll
  for (int g=0;g<4;g++){
    bias0[g] = bih0[g*512+col_own] + bhh0[g*512+col_own];
    bias1[g] = bih1[g*512+col_own] + bhh1[g*512+col_own];
  }
  c0r = c0in[          bb_own*512 + col_own];
  c1r = c0in[32768   + bb_own*512 + col_own];
  float blin_r = blin[0];

  // ---- init h rings (agent stores: cross-XCD readers next iter) ----
  {
    int gidx = wg*256 + tid;            // [0, 65536)
    if (gidx < 32768) st_agent(&ring0[32768 + gidx], h0in[gidx]);
    else              st_agent(&ring1[32768 + (gidx - 32768)], h0in[gidx]);
  }

  unsigned phase = 1;
  gridbar(flags, rel, wg, tid, phase);

  float acc[4][2][4];

  // ---- main pipelined loop: one grid barrier per iteration ----
  for (int t = 0; t <= TT+1; ++t){
    if (t < TT){  // layer 0, step t
      #pragma unroll
      for (int i=0;i<4;i++)
        #pragma unroll
        for (int j=0;j<2;j++)
          #pragma unroll
          for (int g=0;g<4;g++) acc[i][j][g] = 0.f;
      gates_dot<5>(smem, smem + SM_W0,
                   (const float4*)(ring0 + ((t+1)&1)*32768) + bgrp*32*128,
                   (const float4*)x + bgrp*32*16384 + t*32, 16384,
                   tid, bg, cp, kq, acc);
      reduce_cell_wave(acc, kq, bias0, &c0r, bb_own, col_own,
                       ring0 + (t&1)*32768);
    }
    if (t >= 1 && t <= TT){  // layer 1, step t-1
      #pragma unroll
      for (int i=0;i<4;i++)
        #pragma unroll
        for (int j=0;j<2;j++)
          #pragma unroll
          for (int g=0;g<4;g++) acc[i][j][g] = 0.f;
      gates_dot<8>(smem, smem + SM_W1,
                   (const float4*)(ring1 + (t&1)*32768) + bgrp*32*128,
                   (const float4*)(ring0 + ((t+1)&1)*32768) + bgrp*32*128, 128,
                   tid, bg, cp, kq, acc);
      reduce_cell_wave(acc, kq, bias1, &c1r, bb_own, col_own,
                       ring1 + ((t+1)&1)*32768);
    }
    if (t >= 2 && cgrp < 8){  // y, step t-2: 16 WGs x 4 batches each
      int sy = t - 2;
      int yb = bgrp*32 + cgrp*4 + (tid>>6);      // wave w owns one batch
      int k  = tid & 63;
      const float4* row4 = (const float4*)(ring1 + (t&1)*32768 + yb*512);
      const float4* wl4  = (const float4*)(smem + SM_WLIN);
      float4 v0 = row4[k],     w0 = wl4[k];
      float4 v1 = row4[k+64],  w1 = wl4[k+64];
      float p = v0.x*w0.x + v0.y*w0.y + v0.z*w0.z + v0.w*w0.w
              + v1.x*w1.x + v1.y*w1.y + v1.z*w1.z + v1.w*w1.w;
      #pragma unroll
      for (int m=1;m<64;m<<=1) p += __shfl_xor(p, m, 64);
      if (k == 0) st_agent(&out[yb*512 + sy], p + blin_r);
    }
    ++phase;
    gridbar(flags, rel, wg, tid, phase);
  }
}

extern "C" void kernel_launch(void* const* d_in, const int* in_sizes, int n_in,
                              void* d_out, int out_size, void* d_ws, size_t ws_size,
                              hipStream_t stream)
{
  (void)in_sizes; (void)n_in; (void)out_size; (void)ws_size;
  const float* x    = (const float*)d_in[0];
  const float* h0   = (const float*)d_in[1];
  const float* c0   = (const float*)d_in[2];
  const float* wih0 = (const float*)d_in[3];
  const float* whh0 = (const float*)d_in[4];
  const float* bih0 = (const float*)d_in[5];
  const float* bhh0 = (const float*)d_in[6];
  const float* wih1 = (const float*)d_in[7];
  const float* whh1 = (const float*)d_in[8];
  const float* bih1 = (const float*)d_in[9];
  const float* bhh1 = (const float*)d_in[10];
  const float* wlin = (const float*)d_in[11];
  const float* blin = (const float*)d_in[12];
  float* outp = (float*)d_out;
  float* wsp  = (float*)d_ws;

  // zero flags (16KB) + release lines (2KB); rings fully rewritten by the kernel
  hipMemsetAsync(d_ws, 0, 18432, stream);

  void* args[] = { &x, &h0, &c0, &wih0, &whh0, &bih0, &bhh0,
                   &wih1, &whh1, &bih1, &bhh1, &wlin, &blin, &outp, &wsp };
  hipLaunchCooperativeKernel((const void*)lstm_pers, dim3(NWG), dim3(256), args, 0, stream);
}

// Round 7
// 10386.655 us; speedup vs baseline: 2.1139x; 1.3520x over previous
//
#include <hip/hip_runtime.h>
#include <math.h>

// Persistent cooperative 2-layer LSTM. Round 7: MFMA engine, W in LDS (bf16
// hi/lo), proven launch/occupancy profile (1 block/CU via big LDS), launch
// fallback. B=64, T=512, D=128, H=512. 256 WGs x 256 threads (4 waves).
// WG w: bgrp = w&1 (32 batches), cgrp = w>>1 (4 h-cols => 16 gate-rows).
// Waves: wid = tid>>6: layer_w = wid>>1, khalf = wid&1.
//   L0 waves: K=640 ([h0(t-1);x_t]), khalf*320..+320 -> 10 K-frags of 32.
//   L1 waves: K=1024 ([h1(t-2);h0(t-1)]), khalf*512..+512 -> 16 K-frags.
// Split precision: gates = Whi*hhi + Whi*hlo + Wlo*hhi (fp32 accum, err ~2^-17).
// A-side: fp32 float4 loads from rings/x (proven path), cvt to bf16 hi/lo in
// registers. Rings fp32; ring writes 32-bit relaxed-agent stores (proven).
// D partials via LDS RED buffer; activation 1 cell/thread.
// Pipeline: iter t = L0 step t, L1 step t-1, y step t-2. 514 iterations, one
// grid barrier each (round-3/4 topology: flags + WG0 aggregate + 32 rel lines).
//
// ws layout (bytes): flags 256*64 @ 0; rel 32*64 @ 16384; floats @ 20480:
// ring0[2][64][512], ring1[2][64][512].

#define TT 512
#define NWG 256

typedef __attribute__((ext_vector_type(8))) short short8;
typedef __attribute__((ext_vector_type(4))) float f32x4;

// red[layer][khalf][m 0..31][n 0..16pad]
#define RED(L,K,M,N) (((((L)*2+(K))*32+(M))*17)+(N))
#define RED_TOT (2*2*32*17)
// W LDS: 52 frags (L0: 2x10, L1: 2x16) x 4 kslots x 16 n x 8 bf16
#define WLDS_TOT (52*4*16*8)

__device__ __forceinline__ float fsigmoid(float v){ return 1.f/(1.f+__expf(-v)); }
__device__ __forceinline__ float ftanh(float v){ return 2.f/(1.f+__expf(-2.f*v)) - 1.f; }

__device__ __forceinline__ unsigned short f2bf(float f){
  unsigned u = __float_as_uint(f);
  unsigned r = ((u>>16)&1u) + 0x7FFFu;
  return (unsigned short)((u + r)>>16);
}
__device__ __forceinline__ float bf2f(unsigned short s){
  return __uint_as_float(((unsigned)s)<<16);
}
__device__ __forceinline__ void cvt8(const float4& a, const float4& b,
                                     short8& hi, short8& lo){
  float v[8] = {a.x,a.y,a.z,a.w,b.x,b.y,b.z,b.w};
  #pragma unroll
  for (int i=0;i<8;i++){
    unsigned short h = f2bf(v[i]);
    unsigned short l = f2bf(v[i] - bf2f(h));
    ((unsigned short*)&hi)[i] = h;
    ((unsigned short*)&lo)[i] = l;
  }
}

__device__ __forceinline__ void st_agent_f(float* p, float v){
  __hip_atomic_store(p, v, __ATOMIC_RELAXED, __HIP_MEMORY_SCOPE_AGENT);
}

// Proven barrier (rounds 3/4): per-WG arrival lines, WG0-wave0 aggregate,
// 32 replicated release lines (<=8 pollers each).
__device__ __forceinline__ void gridbar(unsigned* flags, unsigned* rel,
                                        int wg, int tid, unsigned phase){
  asm volatile("s_waitcnt vmcnt(0)" ::: "memory");  // ring stores complete
  __syncthreads();
  if (tid == 0)
    __hip_atomic_store(&flags[wg*16], phase, __ATOMIC_RELAXED, __HIP_MEMORY_SCOPE_AGENT);
  if (wg == 0 && tid < 64){
    for(;;){
      bool ok = true;
      #pragma unroll
      for (int i=0;i<4;i++){
        unsigned v = __hip_atomic_load(&flags[(tid*4+i)*16], __ATOMIC_RELAXED, __HIP_MEMORY_SCOPE_AGENT);
        ok &= (v >= phase);
      }
      if (__all(ok)) break;
      __builtin_amdgcn_s_sleep(2);
    }
    if (tid < 32)
      __hip_atomic_store(&rel[tid*16], phase, __ATOMIC_RELAXED, __HIP_MEMORY_SCOPE_AGENT);
  }
  if (tid == 0 && wg != 0){
    unsigned* myrel = &rel[(wg>>3)*16];
    while (__hip_atomic_load(myrel, __ATOMIC_RELAXED, __HIP_MEMORY_SCOPE_AGENT) < phase)
      __builtin_amdgcn_s_sleep(4);
  }
  __syncthreads();
  __builtin_amdgcn_fence(__ATOMIC_ACQUIRE, "agent");  // invalidate stale L1/L2
}

__global__ __launch_bounds__(256, 1) void lstm_pers(
    const float* __restrict__ x,    const float* __restrict__ h0in, const float* __restrict__ c0in,
    const float* __restrict__ wih0, const float* __restrict__ whh0,
    const float* __restrict__ bih0, const float* __restrict__ bhh0,
    const float* __restrict__ wih1, const float* __restrict__ whh1,
    const float* __restrict__ bih1, const float* __restrict__ bhh1,
    const float* __restrict__ wlin, const float* __restrict__ blin,
    float* __restrict__ out, float* ws)
{
  __shared__ __align__(16) unsigned short wlds_hi[WLDS_TOT];   // 53,248 B
  __shared__ __align__(16) unsigned short wlds_lo[WLDS_TOT];   // 53,248 B
  __shared__ __align__(16) float red[RED_TOT];                 //  8,704 B
  const int tid = threadIdx.x, wg = blockIdx.x;
  const int lane = tid & 63;
  const int wid  = tid >> 6;
  const int layer_w = wid >> 1;        // this wave's GEMM layer
  const int khalf   = wid & 1;         // this wave's K half
  const int bgrp = wg & 1;
  const int cgrp = wg >> 1;
  const int colbase = cgrp*4;

  const int kfcount  = layer_w ? 16 : 10;
  const int kbase    = layer_w ? (khalf*512) : (khalf*320);
  const int fragbase = layer_w ? (20 + khalf*16) : (khalf*10);

  unsigned* flags = (unsigned*)ws;                  // 256 x 64B lines
  unsigned* rel   = ((unsigned*)ws) + 4096;         // 32 x 64B lines @ 16384
  float* ring0 = ws + 5120;                         // fp32 [2][64][512] @ 20480
  float* ring1 = ws + 5120 + 65536;

  // ---- W (bf16 hi/lo) into LDS, once. chunk c = ((frag*4+kslot)*16+n), 8 k each ----
  for (int i = 0; i < 13; ++i){
    int c = tid + 256*i;                 // [0, 3328)
    int frag = c >> 6, rem = c & 63, ks = rem >> 4, n = rem & 15;
    int layer, kh, kf;
    if (frag < 20){ layer = 0; kh = frag/10; kf = frag - kh*10; }
    else          { int g = frag-20; layer = 1; kh = g>>4; kf = g&15; }
    int kb = layer ? kh*512 : kh*320;
    int kk = kb + kf*32 + ks*8;
    int wrow = (n>>2)*512 + colbase + (n&3);
    const float* src; long off;
    if (layer == 0){
      if (kk < 512){ src = whh0; off = (long)wrow*512 + kk; }
      else         { src = wih0; off = (long)wrow*128 + (kk-512); }
    } else {
      if (kk < 512){ src = whh1; off = (long)wrow*512 + kk; }
      else         { src = wih1; off = (long)wrow*512 + (kk-512); }
    }
    float4 a = *(const float4*)(src + off);
    float4 b = *(const float4*)(src + off + 4);
    short8 hi, lo; cvt8(a, b, hi, lo);
    *(short8*)(wlds_hi + (size_t)c*8) = hi;
    *(short8*)(wlds_lo + (size_t)c*8) = lo;
  }

  // ---- per-thread activation-role state ----
  const int layer_a = tid >> 7;          // 0/1
  const int cell    = tid & 127;
  const int m_l     = cell >> 2;         // 0..31 local batch
  const int cl      = cell & 3;          // 0..3 local col
  const int col_own = colbase + cl;
  const int bb_a    = bgrp*32 + m_l;
  float biasr[4], cst;
  #pragma unroll
  for (int g=0; g<4; ++g){
    biasr[g] = layer_a ? (bih1[g*512+col_own] + bhh1[g*512+col_own])
                       : (bih0[g*512+col_own] + bhh0[g*512+col_own]);
  }
  cst = c0in[layer_a*32768 + bb_a*512 + col_own];
  float blin_r = blin[0];

  // ---- y-role state: lane k holds wlin[8k..8k+8) ----
  float wl[8];
  {
    const float4* wp = (const float4*)wlin + (lane*2);
    float4 w0 = wp[0], w1 = wp[1];
    wl[0]=w0.x; wl[1]=w0.y; wl[2]=w0.z; wl[3]=w0.w;
    wl[4]=w1.x; wl[5]=w1.y; wl[6]=w1.z; wl[7]=w1.w;
  }

  // ---- init h rings (slot 1) from h0in, fp32 agent stores (proven) ----
  {
    int gidx = wg*256 + tid;             // [0, 65536)
    if (gidx < 32768) st_agent_f(&ring0[32768 + gidx], h0in[gidx]);
    else              st_agent_f(&ring1[32768 + (gidx - 32768)], h0in[gidx]);
  }

  unsigned phase = 1;
  gridbar(flags, rel, wg, tid, phase);   // also covers wlds writes (syncthreads)

  const int m0 = bgrp*32 + (lane & 15);
  const int m1 = m0 + 16;
  const int kslot = lane >> 4;
  const int nlane = lane & 15;

  // ---- main loop: one grid barrier per iteration ----
  for (int t = 0; t <= TT+1; ++t){
    const bool actw = layer_w ? (t >= 1 && t <= TT) : (t < TT);
    if (actw){
      const float *rA, *rB;
      if (layer_w == 0){
        rA = ring0 + ((t+1)&1)*32768;     // h0(t-1)
        rB = 0;
      } else {
        rA = ring1 + (t&1)*32768;         // h1(t-2)
        rB = ring0 + ((t+1)&1)*32768;     // h0(t-1)
      }
      f32x4 acc0 = {0.f,0.f,0.f,0.f}, acc1 = {0.f,0.f,0.f,0.f};
      for (int kf=0; kf<kfcount; ++kf){
        int kk = kbase + kf*32 + kslot*8;
        const float *p0, *p1;
        if (layer_w == 0 && kk >= 512){
          int d = kk - 512;               // x columns
          p0 = x + (size_t)m0*65536 + (size_t)t*128 + d;
          p1 = x + (size_t)m1*65536 + (size_t)t*128 + d;
        } else {
          const float* base; int kloc;
          if (layer_w == 1 && kk >= 512){ base = rB; kloc = kk-512; }
          else                          { base = rA; kloc = kk;    }
          p0 = base + m0*512 + kloc;
          p1 = base + m1*512 + kloc;
        }
        float4 u0 = *(const float4*)p0, u1 = *(const float4*)(p0+4);
        float4 v0 = *(const float4*)p1, v1 = *(const float4*)(p1+4);
        short8 a0h,a0l,a1h,a1l;
        cvt8(u0,u1,a0h,a0l);
        cvt8(v0,v1,a1h,a1l);
        int c = ((fragbase + kf)*4 + kslot)*16 + nlane;
        short8 bh = *(const short8*)(wlds_hi + (size_t)c*8);
        short8 bl = *(const short8*)(wlds_lo + (size_t)c*8);
        acc0 = __builtin_amdgcn_mfma_f32_16x16x32_bf16(a0h, bh, acc0, 0,0,0);
        acc0 = __builtin_amdgcn_mfma_f32_16x16x32_bf16(a0l, bh, acc0, 0,0,0);
        acc0 = __builtin_amdgcn_mfma_f32_16x16x32_bf16(a0h, bl, acc0, 0,0,0);
        acc1 = __builtin_amdgcn_mfma_f32_16x16x32_bf16(a1h, bh, acc1, 0,0,0);
        acc1 = __builtin_amdgcn_mfma_f32_16x16x32_bf16(a1l, bh, acc1, 0,0,0);
        acc1 = __builtin_amdgcn_mfma_f32_16x16x32_bf16(a1h, bl, acc1, 0,0,0);
      }
      // D partials -> LDS. D layout (m89): col n = lane&15, row = (lane>>4)*4+r.
      #pragma unroll
      for (int r=0; r<4; ++r){
        int mm = kslot*4 + r;
        red[RED(layer_w, khalf, mm,    nlane)] = acc0[r];
        red[RED(layer_w, khalf, 16+mm, nlane)] = acc1[r];
      }
    }
    __syncthreads();

    // ---- activation: one cell per thread ----
    {
      const bool acta = layer_a ? (t >= 1 && t <= TT) : (t < TT);
      if (acta){
        float g4[4];
        #pragma unroll
        for (int g=0; g<4; ++g){
          int n = g*4 + cl;
          g4[g] = red[RED(layer_a,0,m_l,n)] + red[RED(layer_a,1,m_l,n)] + biasr[g];
        }
        float gi = fsigmoid(g4[0]);
        float gf = fsigmoid(g4[1]);
        float gg = ftanh   (g4[2]);
        float go = fsigmoid(g4[3]);
        float c = gf*cst + gi*gg;
        cst = c;
        float h = go * ftanh(c);
        int off = (layer_a ? ((t+1)&1) : (t&1))*32768 + bb_a*512 + col_own;
        if (layer_a) st_agent_f(&ring1[off], h);
        else         st_agent_f(&ring0[off], h);
      }
    }

    // ---- y projection, step t-2: 16 WGs x 4 batches (one per wave) ----
    if (t >= 2 && cgrp < 8){
      int sy = t - 2;
      int yb = bgrp*32 + cgrp*4 + wid;
      const float4* row4 = (const float4*)(ring1 + (t&1)*32768 + yb*512) + lane*2;
      float4 v0 = row4[0], v1 = row4[1];
      float p = v0.x*wl[0] + v0.y*wl[1] + v0.z*wl[2] + v0.w*wl[3]
              + v1.x*wl[4] + v1.y*wl[5] + v1.z*wl[6] + v1.w*wl[7];
      #pragma unroll
      for (int m=1; m<64; m<<=1) p += __shfl_xor(p, m, 64);
      if (lane == 0) st_agent_f(&out[yb*512 + sy], p + blin_r);
    }

    ++phase;
    gridbar(flags, rel, wg, tid, phase);
  }
}

extern "C" void kernel_launch(void* const* d_in, const int* in_sizes, int n_in,
                              void* d_out, int out_size, void* d_ws, size_t ws_size,
                              hipStream_t stream)
{
  (void)in_sizes; (void)n_in; (void)out_size; (void)ws_size;
  const float* x    = (const float*)d_in[0];
  const float* h0   = (const float*)d_in[1];
  const float* c0   = (const float*)d_in[2];
  const float* wih0 = (const float*)d_in[3];
  const float* whh0 = (const float*)d_in[4];
  const float* bih0 = (const float*)d_in[5];
  const float* bhh0 = (const float*)d_in[6];
  const float* wih1 = (const float*)d_in[7];
  const float* whh1 = (const float*)d_in[8];
  const float* bih1 = (const float*)d_in[9];
  const float* bhh1 = (const float*)d_in[10];
  const float* wlin = (const float*)d_in[11];
  const float* blin = (const float*)d_in[12];
  float* outp = (float*)d_out;
  float* wsp  = (float*)d_ws;

  // zero flags (16KB) + release lines (2KB); rings fully rewritten by the kernel
  hipMemsetAsync(d_ws, 0, 18432, stream);

  void* args[] = { &x, &h0, &c0, &wih0, &whh0, &bih0, &bhh0,
                   &wih1, &whh1, &bih1, &bhh1, &wlin, &blin, &outp, &wsp };
  hipError_t err = hipLaunchCooperativeKernel((const void*)lstm_pers,
                                              dim3(NWG), dim3(256), args, 0, stream);
  if (err != hipSuccess){
    // Fallback: regular launch. 1 block/CU occupancy (115KB LDS) and exactly
    // 256 blocks on 256 CUs -> all co-resident; grid barrier remains safe.
    hipLaunchKernelGGL(lstm_pers, dim3(NWG), dim3(256), 0, stream,
                       x, h0, c0, wih0, whh0, bih0, bhh0,
                       wih1, whh1, bih1, bhh1, wlin, blin, outp, wsp);
  }
}

// Round 8
// 7775.542 us; speedup vs baseline: 2.8238x; 1.3358x over previous
//
#include <hip/hip_runtime.h>
#include <math.h>

// Persistent cooperative 2-layer LSTM. Round 8: producer-side bf16 conversion.
// B=64, T=512, D=128, H=512. 256 WGs x 256 threads (4 waves), 1 block/CU.
// WG w: bgrp = w&1 (32 batches), cgrp = w>>1 (4 h-cols => 16 gate-rows).
// Waves: wid = tid>>6: layer_w = wid>>1, khalf = wid&1.
//   L0: K=640 ([h0(t-1); x_t]), khalf -> k 0..320 / 320..640 (10 frags).
//   L1: K=1024 ([h1(t-2); h0(t-1)]), khalf -> k 0..512 / 512..1024 (16 frags).
// Split precision: gates = Whi*hhi + Whi*hlo + Wlo*hhi (fp32 accum, ~2^-17).
// Rings: packed bf16 pairs, SEPARATE hi/lo planes (uint = 2 adjacent cols),
// written with proven 32-bit relaxed-agent stores; readers load short8 frags
// directly (no cvt/unpack in the gate loop). x converted once per step into a
// double-buffered LDS stage during the previous iteration. Split barrier:
// arrive after activation; y-proj + x-cvt overlap the wait.
//
// ws layout (bytes): flags 256*64 @0; rel 32*64 @16384; uints @20480:
//   r0h[2][64][256], r0l, r1h, r1l (128KB each).

#define TT 512
#define NWG 256

typedef __attribute__((ext_vector_type(8))) short short8;
typedef __attribute__((ext_vector_type(4))) float f32x4;

#define RED(L,K,M,N) (((((L)*2+(K))*32+(M))*17)+(N))
#define RED_TOT (2*2*32*17)
#define WLDS_TOT (52*4*16*8)     // 52 frags x 4 kslots x 16 n x 8 bf16

__device__ __forceinline__ float fsigmoid(float v){ return 1.f/(1.f+__expf(-v)); }
__device__ __forceinline__ float ftanh(float v){ return 2.f/(1.f+__expf(-2.f*v)) - 1.f; }

__device__ __forceinline__ unsigned short f2bf(float f){
  unsigned u = __float_as_uint(f);
  unsigned r = ((u>>16)&1u) + 0x7FFFu;
  return (unsigned short)((u + r)>>16);
}
__device__ __forceinline__ float bf2f(unsigned short s){
  return __uint_as_float(((unsigned)s)<<16);
}
__device__ __forceinline__ void cvt8(const float4& a, const float4& b,
                                     short8& hi, short8& lo){
  float v[8] = {a.x,a.y,a.z,a.w,b.x,b.y,b.z,b.w};
  #pragma unroll
  for (int i=0;i<8;i++){
    unsigned short h = f2bf(v[i]);
    unsigned short l = f2bf(v[i] - bf2f(h));
    ((unsigned short*)&hi)[i] = h;
    ((unsigned short*)&lo)[i] = l;
  }
}

__device__ __forceinline__ void st_agent_f(float* p, float v){
  __hip_atomic_store(p, v, __ATOMIC_RELAXED, __HIP_MEMORY_SCOPE_AGENT);
}
__device__ __forceinline__ void st_agent_u32(unsigned* p, unsigned v){
  __hip_atomic_store(p, v, __ATOMIC_RELAXED, __HIP_MEMORY_SCOPE_AGENT);
}

// Proven barrier topology (rounds 3-7), split into arrive/wait.
__device__ __forceinline__ void gb_arrive(unsigned* flags, int wg, int tid, unsigned phase){
  asm volatile("s_waitcnt vmcnt(0)" ::: "memory");  // ring stores complete
  __syncthreads();
  if (tid == 0)
    __hip_atomic_store(&flags[wg*16], phase, __ATOMIC_RELAXED, __HIP_MEMORY_SCOPE_AGENT);
}
__device__ __forceinline__ void gb_wait(unsigned* flags, unsigned* rel,
                                        int wg, int tid, unsigned phase){
  if (wg == 0 && tid < 64){
    for(;;){
      bool ok = true;
      #pragma unroll
      for (int i=0;i<4;i++){
        unsigned v = __hip_atomic_load(&flags[(tid*4+i)*16], __ATOMIC_RELAXED, __HIP_MEMORY_SCOPE_AGENT);
        ok &= (v >= phase);
      }
      if (__all(ok)) break;
      __builtin_amdgcn_s_sleep(2);
    }
    if (tid < 32)
      __hip_atomic_store(&rel[tid*16], phase, __ATOMIC_RELAXED, __HIP_MEMORY_SCOPE_AGENT);
  }
  if (tid == 0 && wg != 0){
    unsigned* myrel = &rel[(wg>>3)*16];
    while (__hip_atomic_load(myrel, __ATOMIC_RELAXED, __HIP_MEMORY_SCOPE_AGENT) < phase)
      __builtin_amdgcn_s_sleep(4);
  }
  __syncthreads();
  __builtin_amdgcn_fence(__ATOMIC_ACQUIRE, "agent");  // invalidate stale L1/L2
}

// Gate MFMA loop. Static trip count / branches; A-frags loaded directly as
// short8 from packed bf16 rings or the LDS x-stage. 6 MFMA per kf.
template<int KFC, int LAYER, int KHALF>
__device__ __forceinline__ void gates_mfma(
    const unsigned* __restrict__ rAh, const unsigned* __restrict__ rAl,
    const unsigned* __restrict__ rBh, const unsigned* __restrict__ rBl,
    const unsigned* xsh_t, const unsigned* xsl_t,
    const unsigned short* wh, const unsigned short* wl_,
    int m0, int m1, int kslot, int nlane, int fragbase,
    f32x4& acc0, f32x4& acc1)
{
  constexpr int KB = LAYER ? (KHALF*512) : (KHALF*320);
  #pragma unroll
  for (int kf=0; kf<KFC; ++kf){
    short8 a0h,a0l,a1h,a1l;
    if (LAYER==0 && KHALF==1 && kf>=6){
      int d2 = (kf-6)*16 + kslot*4;          // uint offset within x row
      a0h = *(const short8*)(xsh_t + (m0&31)*68 + d2);
      a0l = *(const short8*)(xsl_t + (m0&31)*68 + d2);
      a1h = *(const short8*)(xsh_t + (m1&31)*68 + d2);
      a1l = *(const short8*)(xsl_t + (m1&31)*68 + d2);
    } else {
      int kk = KB + kf*32 + kslot*8;
      const unsigned *bh, *bl; int k2;
      if (LAYER==1 && KHALF==1){ bh = rBh; bl = rBl; k2 = (kk-512)>>1; }
      else                     { bh = rAh; bl = rAl; k2 = kk>>1;       }
      a0h = *(const short8*)(bh + m0*256 + k2);
      a0l = *(const short8*)(bl + m0*256 + k2);
      a1h = *(const short8*)(bh + m1*256 + k2);
      a1l = *(const short8*)(bl + m1*256 + k2);
    }
    int c = ((fragbase + kf)*4 + kslot)*16 + nlane;
    short8 bhW = *(const short8*)(wh  + (size_t)c*8);
    short8 blW = *(const short8*)(wl_ + (size_t)c*8);
    acc0 = __builtin_amdgcn_mfma_f32_16x16x32_bf16(a0h, bhW, acc0, 0,0,0);
    acc0 = __builtin_amdgcn_mfma_f32_16x16x32_bf16(a0l, bhW, acc0, 0,0,0);
    acc0 = __builtin_amdgcn_mfma_f32_16x16x32_bf16(a0h, blW, acc0, 0,0,0);
    acc1 = __builtin_amdgcn_mfma_f32_16x16x32_bf16(a1h, bhW, acc1, 0,0,0);
    acc1 = __builtin_amdgcn_mfma_f32_16x16x32_bf16(a1l, bhW, acc1, 0,0,0);
    acc1 = __builtin_amdgcn_mfma_f32_16x16x32_bf16(a1h, blW, acc1, 0,0,0);
  }
}

__global__ __launch_bounds__(256, 1) void lstm_pers(
    const float* __restrict__ x,    const float* __restrict__ h0in, const float* __restrict__ c0in,
    const float* __restrict__ wih0, const float* __restrict__ whh0,
    const float* __restrict__ bih0, const float* __restrict__ bhh0,
    const float* __restrict__ wih1, const float* __restrict__ whh1,
    const float* __restrict__ bih1, const float* __restrict__ bhh1,
    const float* __restrict__ wlin, const float* __restrict__ blin,
    float* __restrict__ out, float* ws)
{
  __shared__ __align__(16) unsigned short wlds_hi[WLDS_TOT];   // 53,248 B
  __shared__ __align__(16) unsigned short wlds_lo[WLDS_TOT];   // 53,248 B
  __shared__ __align__(16) float red[RED_TOT];                 //  8,704 B
  __shared__ __align__(16) unsigned xsh_s[2*2176];             // 17,408 B (32x68 pad)
  __shared__ __align__(16) unsigned xsl_s[2*2176];             // 17,408 B
  const int tid = threadIdx.x, wg = blockIdx.x;
  const int lane = tid & 63;
  const int wid  = tid >> 6;
  const int layer_w = wid >> 1;
  const int khalf   = wid & 1;
  const int bgrp = wg & 1;
  const int cgrp = wg >> 1;
  const int colbase = cgrp*4;
  const int fragbase = layer_w ? (20 + khalf*16) : (khalf*10);

  unsigned* flags = (unsigned*)ws;                  // 256 x 64B lines
  unsigned* rel   = ((unsigned*)ws) + 4096;         // 32 x 64B lines @16384
  unsigned* r0h = ((unsigned*)ws) + 5120;           // [2][64][256] each
  unsigned* r0l = r0h + 32768;
  unsigned* r1h = r0h + 65536;
  unsigned* r1l = r0h + 98304;

  // ---- W (bf16 hi/lo) into LDS, once ----
  for (int i = 0; i < 13; ++i){
    int c = tid + 256*i;                 // [0, 3328)
    int frag = c >> 6, rem = c & 63, ks = rem >> 4, n = rem & 15;
    int layer, kh, kf;
    if (frag < 20){ layer = 0; kh = frag/10; kf = frag - kh*10; }
    else          { int g = frag-20; layer = 1; kh = g>>4; kf = g&15; }
    int kb = layer ? kh*512 : kh*320;
    int kk = kb + kf*32 + ks*8;
    int wrow = (n>>2)*512 + colbase + (n&3);
    const float* src; long off;
    if (layer == 0){
      if (kk < 512){ src = whh0; off = (long)wrow*512 + kk; }
      else         { src = wih0; off = (long)wrow*128 + (kk-512); }
    } else {
      if (kk < 512){ src = whh1; off = (long)wrow*512 + kk; }
      else         { src = wih1; off = (long)wrow*512 + (kk-512); }
    }
    float4 a = *(const float4*)(src + off);
    float4 b = *(const float4*)(src + off + 4);
    short8 hi, lo; cvt8(a, b, hi, lo);
    *(short8*)(wlds_hi + (size_t)c*8) = hi;
    *(short8*)(wlds_lo + (size_t)c*8) = lo;
  }

  // ---- activation-role state ----
  const int layer_a = tid >> 7;
  const int cell    = tid & 127;
  const int m_l     = cell >> 2;
  const int cl      = cell & 3;
  const int col_own = colbase + cl;
  const int bb_a    = bgrp*32 + m_l;
  float biasr[4], cst;
  #pragma unroll
  for (int g=0; g<4; ++g){
    biasr[g] = layer_a ? (bih1[g*512+col_own] + bhh1[g*512+col_own])
                       : (bih0[g*512+col_own] + bhh0[g*512+col_own]);
  }
  cst = c0in[layer_a*32768 + bb_a*512 + col_own];
  float blin_r = blin[0];

  // ---- y-role state: lane holds wlin[8k..8k+8) ----
  float wl[8];
  {
    const float4* wp = (const float4*)wlin + (lane*2);
    float4 w0 = wp[0], w1 = wp[1];
    wl[0]=w0.x; wl[1]=w0.y; wl[2]=w0.z; wl[3]=w0.w;
    wl[4]=w1.x; wl[5]=w1.y; wl[6]=w1.z; wl[7]=w1.w;
  }

  // ---- init h rings (slot 1) packed bf16 hi/lo, 32-bit agent stores ----
  {
    int gidx = wg*256 + tid;             // [0, 65536)
    if (!(gidx & 1)){
      float v0 = h0in[gidx], v1 = h0in[gidx+1];
      unsigned short hA = f2bf(v0), lA = f2bf(v0 - bf2f(hA));
      unsigned short hB = f2bf(v1), lB = f2bf(v1 - bf2f(hB));
      unsigned uh = (unsigned)hA | ((unsigned)hB<<16);
      unsigned ul = (unsigned)lA | ((unsigned)lB<<16);
      int half = gidx >> 15;
      int idx  = (gidx & 32767) >> 1;
      unsigned* ph = half ? r1h : r0h;
      unsigned* pl = half ? r1l : r0l;
      st_agent_u32(ph + 16384 + idx, uh);
      st_agent_u32(pl + 16384 + idx, ul);
    }
  }

  // ---- x stage for t=0 ----
  {
    int m = tid>>3, dd = (tid&7)*16;
    const float* xp = x + ((size_t)(bgrp*32+m))*65536 + 0*128 + dd;
    float4 v0 = *(const float4*)xp,      v1 = *(const float4*)(xp+4),
           v2 = *(const float4*)(xp+8),  v3 = *(const float4*)(xp+12);
    float vv[16] = {v0.x,v0.y,v0.z,v0.w, v1.x,v1.y,v1.z,v1.w,
                    v2.x,v2.y,v2.z,v2.w, v3.x,v3.y,v3.z,v3.w};
    unsigned uh[8], ul[8];
    #pragma unroll
    for (int j=0;j<8;j++){
      unsigned short hA = f2bf(vv[2*j]),   hB = f2bf(vv[2*j+1]);
      unsigned short lA = f2bf(vv[2*j]-bf2f(hA)), lB = f2bf(vv[2*j+1]-bf2f(hB));
      uh[j] = (unsigned)hA | ((unsigned)hB<<16);
      ul[j] = (unsigned)lA | ((unsigned)lB<<16);
    }
    unsigned* dh = xsh_s + m*68 + (dd>>1);
    unsigned* dl = xsl_s + m*68 + (dd>>1);
    *(uint4*)dh     = make_uint4(uh[0],uh[1],uh[2],uh[3]);
    *(uint4*)(dh+4) = make_uint4(uh[4],uh[5],uh[6],uh[7]);
    *(uint4*)dl     = make_uint4(ul[0],ul[1],ul[2],ul[3]);
    *(uint4*)(dl+4) = make_uint4(ul[4],ul[5],ul[6],ul[7]);
  }

  unsigned phase = 1;
  gb_arrive(flags, wg, tid, phase);
  gb_wait(flags, rel, wg, tid, phase);
  ++phase;

  const int m0 = bgrp*32 + (lane & 15);
  const int m1 = m0 + 16;
  const int kslot = lane >> 4;
  const int nlane = lane & 15;

  for (int t = 0; t <= TT+1; ++t){
    // ---- gates (MFMA) ----
    const bool actw = layer_w ? (t >= 1 && t <= TT) : (t < TT);
    if (actw){
      const unsigned *rAh,*rAl,*rBh,*rBl;
      if (layer_w == 0){
        int s = ((t+1)&1)*16384;          // h0(t-1)
        rAh = r0h+s; rAl = r0l+s; rBh = 0; rBl = 0;
      } else {
        int sA = (t&1)*16384;             // h1(t-2)
        int sB = ((t+1)&1)*16384;         // h0(t-1)
        rAh = r1h+sA; rAl = r1l+sA; rBh = r0h+sB; rBl = r0l+sB;
      }
      const unsigned* xsh_t = xsh_s + (t&1)*2176;
      const unsigned* xsl_t = xsl_s + (t&1)*2176;
      f32x4 acc0 = {0.f,0.f,0.f,0.f}, acc1 = {0.f,0.f,0.f,0.f};
      if (layer_w == 0){
        if (khalf == 0) gates_mfma<10,0,0>(rAh,rAl,rBh,rBl,xsh_t,xsl_t,wlds_hi,wlds_lo,m0,m1,kslot,nlane,fragbase,acc0,acc1);
        else            gates_mfma<10,0,1>(rAh,rAl,rBh,rBl,xsh_t,xsl_t,wlds_hi,wlds_lo,m0,m1,kslot,nlane,fragbase,acc0,acc1);
      } else {
        if (khalf == 0) gates_mfma<16,1,0>(rAh,rAl,rBh,rBl,xsh_t,xsl_t,wlds_hi,wlds_lo,m0,m1,kslot,nlane,fragbase,acc0,acc1);
        else            gates_mfma<16,1,1>(rAh,rAl,rBh,rBl,xsh_t,xsl_t,wlds_hi,wlds_lo,m0,m1,kslot,nlane,fragbase,acc0,acc1);
      }
      // D layout (m89): col n = lane&15, row = (lane>>4)*4+r.
      #pragma unroll
      for (int r=0; r<4; ++r){
        int mm = kslot*4 + r;
        red[RED(layer_w, khalf, mm,    nlane)] = acc0[r];
        red[RED(layer_w, khalf, 16+mm, nlane)] = acc1[r];
      }
    }
    __syncthreads();

    // ---- activation: one cell per thread; pair-pack ring writes ----
    {
      const bool acta = layer_a ? (t >= 1 && t <= TT) : (t < TT);
      float h = 0.f;
      if (acta){
        float g4[4];
        #pragma unroll
        for (int g=0; g<4; ++g){
          int n = g*4 + cl;
          g4[g] = red[RED(layer_a,0,m_l,n)] + red[RED(layer_a,1,m_l,n)] + biasr[g];
        }
        float gi = fsigmoid(g4[0]);
        float gf = fsigmoid(g4[1]);
        float gg = ftanh   (g4[2]);
        float go = fsigmoid(g4[3]);
        float c = gf*cst + gi*gg;
        cst = c;
        h = go * ftanh(c);
      }
      float h_oth = __shfl_xor(h, 1, 64);
      if (acta && !(tid & 1)){
        unsigned short hA = f2bf(h),     lA = f2bf(h - bf2f(hA));
        unsigned short hB = f2bf(h_oth), lB = f2bf(h_oth - bf2f(hB));
        unsigned uh = (unsigned)hA | ((unsigned)hB<<16);
        unsigned ul = (unsigned)lA | ((unsigned)lB<<16);
        int slot = layer_a ? ((t+1)&1) : (t&1);
        int off = slot*16384 + bb_a*256 + (col_own>>1);
        if (layer_a){ st_agent_u32(r1h + off, uh); st_agent_u32(r1l + off, ul); }
        else        { st_agent_u32(r0h + off, uh); st_agent_u32(r0l + off, ul); }
      }
    }

    gb_arrive(flags, wg, tid, phase);

    // ==== overlap region: only old-slot / pure-input reads ====
    if (t >= 2 && cgrp < 8){           // y(t-2): 16 WGs x 4 batches
      int sy = t - 2;
      int yb = bgrp*32 + cgrp*4 + wid;
      const uint4* qh = (const uint4*)(r1h + (t&1)*16384 + yb*256) + lane;
      const uint4* ql = (const uint4*)(r1l + (t&1)*16384 + yb*256) + lane;
      uint4 a = qh[0], b = ql[0];
      float p = 0.f;
      {
        unsigned qa, qb; float e0, e1;
        qa=a.x; qb=b.x;
        e0 = __uint_as_float(qa<<16) + __uint_as_float(qb<<16);
        e1 = __uint_as_float(qa & 0xFFFF0000u) + __uint_as_float(qb & 0xFFFF0000u);
        p += e0*wl[0] + e1*wl[1];
        qa=a.y; qb=b.y;
        e0 = __uint_as_float(qa<<16) + __uint_as_float(qb<<16);
        e1 = __uint_as_float(qa & 0xFFFF0000u) + __uint_as_float(qb & 0xFFFF0000u);
        p += e0*wl[2] + e1*wl[3];
        qa=a.z; qb=b.z;
        e0 = __uint_as_float(qa<<16) + __uint_as_float(qb<<16);
        e1 = __uint_as_float(qa & 0xFFFF0000u) + __uint_as_float(qb & 0xFFFF0000u);
        p += e0*wl[4] + e1*wl[5];
        qa=a.w; qb=b.w;
        e0 = __uint_as_float(qa<<16) + __uint_as_float(qb<<16);
        e1 = __uint_as_float(qa & 0xFFFF0000u) + __uint_as_float(qb & 0xFFFF0000u);
        p += e0*wl[6] + e1*wl[7];
      }
      #pragma unroll
      for (int m=1; m<64; m<<=1) p += __shfl_xor(p, m, 64);
      if (lane == 0) st_agent_f(&out[yb*512 + sy], p + blin_r);
    }
    if (t+1 < TT){                     // stage x(t+1) into LDS buf (t+1)&1
      int m = tid>>3, dd = (tid&7)*16;
      const float* xp = x + ((size_t)(bgrp*32+m))*65536 + (size_t)(t+1)*128 + dd;
      float4 v0 = *(const float4*)xp,      v1 = *(const float4*)(xp+4),
             v2 = *(const float4*)(xp+8),  v3 = *(const float4*)(xp+12);
      float vv[16] = {v0.x,v0.y,v0.z,v0.w, v1.x,v1.y,v1.z,v1.w,
                      v2.x,v2.y,v2.z,v2.w, v3.x,v3.y,v3.z,v3.w};
      unsigned uh[8], ul[8];
      #pragma unroll
      for (int j=0;j<8;j++){
        unsigned short hA = f2bf(vv[2*j]),   hB = f2bf(vv[2*j+1]);
        unsigned short lA = f2bf(vv[2*j]-bf2f(hA)), lB = f2bf(vv[2*j+1]-bf2f(hB));
        uh[j] = (unsigned)hA | ((unsigned)hB<<16);
        ul[j] = (unsigned)lA | ((unsigned)lB<<16);
      }
      unsigned* dh = xsh_s + ((t+1)&1)*2176 + m*68 + (dd>>1);
      unsigned* dl = xsl_s + ((t+1)&1)*2176 + m*68 + (dd>>1);
      *(uint4*)dh     = make_uint4(uh[0],uh[1],uh[2],uh[3]);
      *(uint4*)(dh+4) = make_uint4(uh[4],uh[5],uh[6],uh[7]);
      *(uint4*)dl     = make_uint4(ul[0],ul[1],ul[2],ul[3]);
      *(uint4*)(dl+4) = make_uint4(ul[4],ul[5],ul[6],ul[7]);
    }
    // ==== end overlap ====

    gb_wait(flags, rel, wg, tid, phase);
    ++phase;
  }
}

extern "C" void kernel_launch(void* const* d_in, const int* in_sizes, int n_in,
                              void* d_out, int out_size, void* d_ws, size_t ws_size,
                              hipStream_t stream)
{
  (void)in_sizes; (void)n_in; (void)out_size; (void)ws_size;
  const float* x    = (const float*)d_in[0];
  const float* h0   = (const float*)d_in[1];
  const float* c0   = (const float*)d_in[2];
  const float* wih0 = (const float*)d_in[3];
  const float* whh0 = (const float*)d_in[4];
  const float* bih0 = (const float*)d_in[5];
  const float* bhh0 = (const float*)d_in[6];
  const float* wih1 = (const float*)d_in[7];
  const float* whh1 = (const float*)d_in[8];
  const float* bih1 = (const float*)d_in[9];
  const float* bhh1 = (const float*)d_in[10];
  const float* wlin = (const float*)d_in[11];
  const float* blin = (const float*)d_in[12];
  float* outp = (float*)d_out;
  float* wsp  = (float*)d_ws;

  // zero flags (16KB) + release lines (2KB); rings fully rewritten by the kernel
  hipMemsetAsync(d_ws, 0, 18432, stream);

  void* args[] = { &x, &h0, &c0, &wih0, &whh0, &bih0, &bhh0,
                   &wih1, &whh1, &bih1, &bhh1, &wlin, &blin, &outp, &wsp };
  hipError_t err = hipLaunchCooperativeKernel((const void*)lstm_pers,
                                              dim3(NWG), dim3(256), args, 0, stream);
  if (err != hipSuccess){
    // Fallback: 1 block/CU (150KB LDS), 256 blocks on 256 CUs -> co-resident.
    hipLaunchKernelGGL(lstm_pers, dim3(NWG), dim3(256), 0, stream,
                       x, h0, c0, wih0, whh0, bih0, bhh0,
                       wih1, whh1, bih1, bhh1, wlin, blin, outp, wsp);
  }
}